// Round 2
// baseline (83.967 us; speedup 1.0000x reference)
//
#include <hip/hip_runtime.h>

#define BM 128
#define BN 64
#define BK 32
#define VIG 0.75f

// Kernel 1: split-K fuzzy-AND accumulation (min-plus GEMM).
// Grid: (N/BM, C/BN, ksplit), 256 threads, each computes an 8x4 output tile.
// LDS tiles stored [K][M] with a 3-bit XOR granule swizzle:
//   element (k, m) lives at k*WIDTH + ((((m>>2) ^ ((k>>2)&7)) << 2) | (m&3)).
// Staging stores: banks = f(granule^swz, m&3) -> exactly 2-way (free, m136).
// Fragment reads: b128, granule permutation only -> broadcast/2-way, free.
__global__ __launch_bounds__(256) void fuzzy_scores_kernel(
    const float* __restrict__ x, const float* __restrict__ w,
    float* __restrict__ out0, float* __restrict__ wsbuf,
    int N, int C, int D, int kchunk)
{
    __shared__ float sA[BK * BM];   // 16 KB
    __shared__ float sB[BK * BN];   //  8 KB

    const int t  = threadIdx.x;
    const int cx = t & 15;          // column group: cols cx*4..+3 (coalesced stores)
    const int ry = t >> 4;          // row group: rows ry*8..+7
    const int bx = blockIdx.x, by = blockIdx.y, bz = blockIdx.z;
    const int d0 = bz * kchunk;

    float acc[8][4];
#pragma unroll
    for (int i = 0; i < 8; ++i)
#pragma unroll
        for (int j = 0; j < 4; ++j) acc[i][j] = 0.f;

    for (int kb = 0; kb < kchunk; kb += BK) {
        if (kb) __syncthreads();    // protect LDS from previous iteration's readers

        // stage A: BK*BM = 4096 floats = 1024 float4, 4 per thread
#pragma unroll
        for (int l = 0; l < 4; ++l) {
            const int q   = l * 256 + t;     // 0..1023
            const int rr  = q >> 3;          // 0..127
            const int kq  = (q & 7) << 2;    // 0,4,...,28
            const int swz = (kq >> 2) & 7;   // constant over kq..kq+3
            const int gb  = ((((rr >> 2) ^ swz) << 2) | (rr & 3));
            const float4 v = *(const float4*)(x + (size_t)(bx * BM + rr) * D + d0 + kb + kq);
            sA[(kq + 0) * BM + gb] = v.x;
            sA[(kq + 1) * BM + gb] = v.y;
            sA[(kq + 2) * BM + gb] = v.z;
            sA[(kq + 3) * BM + gb] = v.w;
        }
        // stage B: BK*BN = 2048 floats = 512 float4, 2 per thread
#pragma unroll
        for (int l = 0; l < 2; ++l) {
            const int q   = l * 256 + t;     // 0..511
            const int rr  = q >> 3;          // 0..63
            const int kq  = (q & 7) << 2;
            const int swz = (kq >> 2) & 7;
            const int gb  = ((((rr >> 2) ^ swz) << 2) | (rr & 3));
            const float4 u = *(const float4*)(w + (size_t)(by * BN + rr) * D + d0 + kb + kq);
            sB[(kq + 0) * BN + gb] = u.x;
            sB[(kq + 1) * BN + gb] = u.y;
            sB[(kq + 2) * BN + gb] = u.z;
            sB[(kq + 3) * BN + gb] = u.w;
        }
        __syncthreads();

#pragma unroll
        for (int k = 0; k < BK; ++k) {
            const int swz = (k >> 2) & 7;
            const float4 a0 = *(const float4*)&sA[k * BM + ((((ry << 1)    ) ^ swz) << 2)];
            const float4 a1 = *(const float4*)&sA[k * BM + ((((ry << 1) + 1) ^ swz) << 2)];
            const float4 b  = *(const float4*)&sB[k * BN + ((cx ^ swz) << 2)];
            const float av[8] = {a0.x, a0.y, a0.z, a0.w, a1.x, a1.y, a1.z, a1.w};
            const float bv[4] = {b.x, b.y, b.z, b.w};
#pragma unroll
            for (int i = 0; i < 8; ++i)
#pragma unroll
                for (int j = 0; j < 4; ++j)
                    acc[i][j] += fminf(av[i], bv[j]);
        }
    }

    float* dst = (bz == 0) ? out0 : (wsbuf + (size_t)(bz - 1) * N * C);
    const int col = by * BN + (cx << 2);
#pragma unroll
    for (int i = 0; i < 8; ++i) {
        const int row = bx * BM + (ry << 3) + i;
        *(float4*)(dst + (size_t)row * C + col) =
            make_float4(acc[i][0], acc[i][1], acc[i][2], acc[i][3]);
    }
}

// Kernel 2: per-row finish. Sums split-K partials, divides by row-sum of x,
// applies vigilance gate, writes final scores, argmax (first index on ties,
// all-zero row -> 0, matching jnp.argmax).
// Grid: N blocks of 256 threads (D == 256).
__global__ __launch_bounds__(256) void fuzzy_finish_kernel(
    const float* __restrict__ x, float* __restrict__ out,
    const float* __restrict__ wsbuf, int N, int C, int D, int ksplit)
{
    const int n = blockIdx.x;
    const int t = threadIdx.x;
    const int lane = t & 63;
    const int wid  = t >> 6;

    // row sum of x
    float v = x[(size_t)n * D + t];
#pragma unroll
    for (int s = 1; s < 64; s <<= 1) v += __shfl_xor(v, s);
    __shared__ float wsum[4];
    if (lane == 0) wsum[wid] = v;
    __syncthreads();
    const float sumx = wsum[0] + wsum[1] + wsum[2] + wsum[3];

    float best = -1.f;
    int   bidx = 0;
    for (int j = 0; j < C; j += 256) {
        const int c = j + t;
        const size_t off = (size_t)n * C + c;
        float raw = out[off];
        for (int p = 1; p < ksplit; ++p)
            raw += wsbuf[(size_t)(p - 1) * N * C + off];
        const float m = raw / sumx;
        const float s = (m >= VIG) ? m : 0.f;
        out[off] = s;
        if (s > best) { best = s; bidx = c; }  // strictly greater: first index wins ties
    }

    // wave argmax reduce (value desc, index asc on ties)
#pragma unroll
    for (int s2 = 1; s2 < 64; s2 <<= 1) {
        const float ov = __shfl_xor(best, s2);
        const int   oi = __shfl_xor(bidx, s2);
        if (ov > best || (ov == best && oi < bidx)) { best = ov; bidx = oi; }
    }
    __shared__ float bvs[4];
    __shared__ int   bis[4];
    if (lane == 0) { bvs[wid] = best; bis[wid] = bidx; }
    __syncthreads();
    if (t == 0) {
        for (int w2 = 1; w2 < 4; ++w2) {
            if (bvs[w2] > best || (bvs[w2] == best && bis[w2] < bidx)) {
                best = bvs[w2];
                bidx = bis[w2];
            }
        }
        out[(size_t)N * C + n] = (float)bidx;
    }
}

extern "C" void kernel_launch(void* const* d_in, const int* in_sizes, int n_in,
                              void* d_out, int out_size, void* d_ws, size_t ws_size,
                              hipStream_t stream) {
    const float* x = (const float*)d_in[0];
    const float* w = (const float*)d_in[1];
    float* out = (float*)d_out;
    float* ws  = (float*)d_ws;

    const int D = 256;
    const int N = in_sizes[0] / D;   // 1024
    const int C = in_sizes[1] / D;   // 512

    const size_t partial_bytes = (size_t)N * C * sizeof(float);  // 2 MB
    int ksplit = 1;
    if (ws_size >= 7 * partial_bytes)      ksplit = 8;   // kchunk == BK: single K-iter
    else if (ws_size >= 3 * partial_bytes) ksplit = 4;
    else if (ws_size >= partial_bytes)     ksplit = 2;
    const int kchunk = D / ksplit;

    dim3 grid(N / BM, C / BN, ksplit);
    fuzzy_scores_kernel<<<grid, 256, 0, stream>>>(x, w, out, ws, N, C, D, kchunk);
    fuzzy_finish_kernel<<<N, 256, 0, stream>>>(x, out, ws, N, C, D, ksplit);
}

// Round 3
// 74.246 us; speedup vs baseline: 1.1309x; 1.1309x over previous
//
#include <hip/hip_runtime.h>

#define VIG   0.75f
#define DD    256   // feature dim (fixed by problem)
#define ROWS  4     // rows per block

// Single fused kernel. Grid: N/ROWS blocks of C threads (C==512).
// Block b handles rows r0..r0+3 for ALL C columns; thread t owns column t.
// x[r][k] is wave-uniform -> compiler emits scalar (s_load) reads: zero VMEM
// pressure. w[t][k] read as 4 consecutive dwordx4 = one full 64B line per lane
// per 16-k chunk -> L2 traffic is exactly (N/ROWS)*|w| = 128 MB, ~3.7us.
// Row-sum, vigilance gate, and per-row argmax all complete in-block:
// no workspace, no second dispatch.
__global__ __launch_bounds__(512, 2) void fuzzy_fused_kernel(
    const float* __restrict__ x, const float* __restrict__ w,
    float* __restrict__ out, int N, int C)
{
    const int t  = threadIdx.x;            // == column index
    const int r0 = blockIdx.x * ROWS;

    __shared__ float part[8];
    __shared__ float redv[ROWS][8];
    __shared__ int   redi[ROWS][8];

    // ---- row sums of x: 128 threads per row, wave-uniform row id ----
    {
        const int rid = t >> 7;            // 0..3 (wave-uniform: 2 waves/row)
        const int j   = t & 127;
        const float* xr = x + (size_t)(r0 + rid) * DD;
        float v = xr[j] + xr[j + 128];
#pragma unroll
        for (int s = 1; s < 64; s <<= 1) v += __shfl_xor(v, s);
        if ((t & 63) == 0) part[t >> 6] = v;
    }
    __syncthreads();
    float sumx[ROWS];
#pragma unroll
    for (int r = 0; r < ROWS; ++r) sumx[r] = part[2 * r] + part[2 * r + 1];

    // ---- main accumulation: 4 rows x 256 d per thread-column ----
    float acc[ROWS] = {0.f, 0.f, 0.f, 0.f};
    const float* wp = w + (size_t)t * DD;
    const float* xb = x + (size_t)r0 * DD;

    for (int k = 0; k < DD; k += 16) {
        const float4 w0 = *(const float4*)(wp + k);
        const float4 w1 = *(const float4*)(wp + k + 4);
        const float4 w2 = *(const float4*)(wp + k + 8);
        const float4 w3 = *(const float4*)(wp + k + 12);
        float wv[16];
        wv[0]  = w0.x; wv[1]  = w0.y; wv[2]  = w0.z; wv[3]  = w0.w;
        wv[4]  = w1.x; wv[5]  = w1.y; wv[6]  = w1.z; wv[7]  = w1.w;
        wv[8]  = w2.x; wv[9]  = w2.y; wv[10] = w2.z; wv[11] = w2.w;
        wv[12] = w3.x; wv[13] = w3.y; wv[14] = w3.z; wv[15] = w3.w;
#pragma unroll
        for (int r = 0; r < ROWS; ++r) {
            const float* xr = xb + r * DD + k;   // wave-uniform address -> s_load
#pragma unroll
            for (int kk = 0; kk < 16; ++kk)
                acc[r] += fminf(xr[kk], wv[kk]);
        }
    }

    // ---- epilogue: gate + store scores + per-row argmax ----
#pragma unroll
    for (int r = 0; r < ROWS; ++r) {
        const float m = acc[r] / sumx[r];          // IEEE divide: matches np gate
        const float s = (m >= VIG) ? m : 0.f;
        out[(size_t)(r0 + r) * C + t] = s;

        float bv = s;
        int   bi = t;
#pragma unroll
        for (int sh = 1; sh < 64; sh <<= 1) {
            const float ov = __shfl_xor(bv, sh);
            const int   oi = __shfl_xor(bi, sh);
            if (ov > bv || (ov == bv && oi < bi)) { bv = ov; bi = oi; }
        }
        if ((t & 63) == 0) { redv[r][t >> 6] = bv; redi[r][t >> 6] = bi; }
    }
    __syncthreads();
    if (t < ROWS) {
        float bv = redv[t][0];
        int   bi = redi[t][0];
#pragma unroll
        for (int q = 1; q < 8; ++q) {
            if (redv[t][q] > bv || (redv[t][q] == bv && redi[t][q] < bi)) {
                bv = redv[t][q];
                bi = redi[t][q];
            }
        }
        out[(size_t)N * C + r0 + t] = (float)bi;   // first-index tie-break; all-zero row -> 0
    }
}

extern "C" void kernel_launch(void* const* d_in, const int* in_sizes, int n_in,
                              void* d_out, int out_size, void* d_ws, size_t ws_size,
                              hipStream_t stream) {
    const float* x = (const float*)d_in[0];
    const float* w = (const float*)d_in[1];
    float* out = (float*)d_out;
    (void)d_ws; (void)ws_size;   // workspace intentionally unused

    const int N = in_sizes[0] / DD;   // 1024
    const int C = in_sizes[1] / DD;   // 512

    fuzzy_fused_kernel<<<N / ROWS, C, 0, stream>>>(x, w, out, N, C);
}